// Round 4
// baseline (341.175 us; speedup 1.0000x reference)
//
#include <hip/hip_runtime.h>
#include <hip/hip_bf16.h>
#include <stdint.h>

#define B_ 2
#define N_ 2048
#define D_ 1024
#define H_ 16
#define MM 4096
#define NN 1024
#define KK 1024

typedef __bf16 bf16;
typedef __bf16 bf16x8 __attribute__((ext_vector_type(8)));
typedef float f32x4 __attribute__((ext_vector_type(4)));

struct __align__(8) bf4 { bf16 v[4]; };

#define LDS_STRIDE 144

#define GLDS(gp, lp)                                                     \
    __builtin_amdgcn_global_load_lds(                                    \
        (const __attribute__((address_space(1))) void*)(gp),             \
        (__attribute__((address_space(3))) void*)(lp), 16, 0, 0)

// ---------------------------------------------------------------- conversions
__global__ __launch_bounds__(256) void k_cvt3(const float* __restrict__ q,
                                              const float* __restrict__ k,
                                              const float* __restrict__ v,
                                              bf16* __restrict__ qb,
                                              bf16* __restrict__ kb,
                                              bf16* __restrict__ vb) {
    const int z = blockIdx.y;
    const float* s = z == 0 ? q : z == 1 ? k : v;
    bf16* d = z == 0 ? qb : z == 1 ? kb : vb;
    size_t i = ((size_t)blockIdx.x * 256 + threadIdx.x) * 8;
    f32x4 a = *(const f32x4*)(s + i);
    f32x4 b = *(const f32x4*)(s + i + 4);
    bf16x8 o;
#pragma unroll
    for (int j = 0; j < 4; ++j) { o[j] = (bf16)a[j]; o[4 + j] = (bf16)b[j]; }
    *(bf16x8*)(d + i) = o;
}

// Wt[n][k] = (bf16)W[k][n], z picks which weight (1024x1024)
__global__ void k_wtt4(const float* __restrict__ Wq, const float* __restrict__ Wk,
                       const float* __restrict__ Wv, const float* __restrict__ Wo,
                       bf16* __restrict__ WqT, bf16* __restrict__ WkT,
                       bf16* __restrict__ WvT, bf16* __restrict__ WoT) {
    const int z = blockIdx.z;
    const float* W = z == 0 ? Wq : z == 1 ? Wk : z == 2 ? Wv : Wo;
    bf16* Wt = z == 0 ? WqT : z == 1 ? WkT : z == 2 ? WvT : WoT;
    __shared__ float t[32][33];
    int bx = blockIdx.x * 32, by = blockIdx.y * 32;
    int tx = threadIdx.x, ty = threadIdx.y;
#pragma unroll
    for (int j = 0; j < 32; j += 8)
        t[ty + j][tx] = W[(size_t)(by + ty + j) * 1024 + bx + tx];
    __syncthreads();
#pragma unroll
    for (int j = 0; j < 32; j += 8)
        Wt[(size_t)(bx + ty + j) * 1024 + by + tx] = (bf16)t[tx][ty + j];
}

// ---------------------------------------------------------------- mask bits
__global__ __launch_bounds__(256) void k_bits(const int* __restrict__ mask,
                                              uint32_t* __restrict__ bits) {
    size_t flat = (size_t)blockIdx.x * 256 + threadIdx.x;
    int col = (int)(flat & (N_ - 1));
    int row = (int)((flat >> 11) & (N_ - 1));
    bool ok = (mask[flat] != 0) && (col <= row);
    unsigned long long bal = __ballot(ok);
    if ((threadIdx.x & 63) == 0)
        *(unsigned long long*)(bits + (flat >> 5)) = bal;
}

// ---------------------------------------------------------------- GEMM core
// C = A @ Bt^T, 128x128 tile, BK=64, 4 waves, global_load_lds w=16 (m97).
__device__ __forceinline__ void mm_core(const bf16* __restrict__ A,
                                        const bf16* __restrict__ Bt,
                                        int bm0, int bn0,
                                        bf16* As, bf16* Bs,
                                        f32x4 (&acc)[4][4]) {
    const int tid = threadIdx.x, w = tid >> 6, lane = tid & 63;
    const int g = lane >> 4, li = lane & 15;
    const int wr = w >> 1, wc = w & 1;

    f32x4 zz = {0.f, 0.f, 0.f, 0.f};
#pragma unroll
    for (int mf = 0; mf < 4; ++mf)
#pragma unroll
        for (int nf = 0; nf < 4; ++nf) acc[mf][nf] = zz;

    auto stage = [&](int k0) {
#pragma unroll
        for (int c = 0; c < 4; ++c) {
            int ch = c * 256 + tid;
            int r = ch >> 3, cl = ch & 7;
            GLDS(A + (size_t)(bm0 + r) * KK + k0 + cl * 8,
                 As + ((size_t)c * 256 + w * 64) * 8);
        }
#pragma unroll
        for (int c = 0; c < 4; ++c) {
            int ch = c * 256 + tid;
            int r = ch >> 3, cl = ch & 7;
            GLDS(Bt + (size_t)(bn0 + r) * KK + k0 + cl * 8,
                 Bs + ((size_t)c * 256 + w * 64) * 8);
        }
    };

    stage(0);
    for (int s = 0; s < KK / 64; ++s) {
        __syncthreads();
#pragma unroll
        for (int kk = 0; kk < 2; ++kk) {
            bf16x8 af[4], bfr[4];
#pragma unroll
            for (int i = 0; i < 4; ++i) {
                af[i] = *(const bf16x8*)(As + (wr * 64 + i * 16 + li) * 64 + kk * 32 + g * 8);
                bfr[i] = *(const bf16x8*)(Bs + (wc * 64 + i * 16 + li) * 64 + kk * 32 + g * 8);
            }
#pragma unroll
            for (int mf = 0; mf < 4; ++mf)
#pragma unroll
                for (int nf = 0; nf < 4; ++nf)
                    acc[mf][nf] = __builtin_amdgcn_mfma_f32_16x16x32_bf16(
                        af[mf], bfr[nf], acc[mf][nf], 0, 0, 0);
        }
        __syncthreads();
        if (s + 1 < KK / 64) stage((s + 1) * 64);
    }
}

// fused Q/K/V projections
__global__ __launch_bounds__(256) void k_proj(const bf16* __restrict__ qb,
                                              const bf16* __restrict__ kb,
                                              const bf16* __restrict__ vb,
                                              const bf16* __restrict__ WqT,
                                              const bf16* __restrict__ WkT,
                                              const bf16* __restrict__ WvT,
                                              bf16* __restrict__ Qh,
                                              bf16* __restrict__ Kh,
                                              bf16* __restrict__ Vt) {
    __shared__ __align__(16) bf16 As[128 * 64];
    __shared__ __align__(16) bf16 Bs[128 * 64];
    const int z = blockIdx.y;
    const bf16* A = z == 0 ? qb : z == 1 ? kb : vb;
    const bf16* Bt = z == 0 ? WqT : z == 1 ? WkT : WvT;
    int bid = blockIdx.x;
    int swz = (bid & 7) * 32 + (bid >> 3);
    int bm0 = (swz >> 3) * 128, bn0 = (swz & 7) * 128;

    f32x4 acc[4][4];
    mm_core(A, Bt, bm0, bn0, As, Bs, acc);

    const int tid = threadIdx.x, w = tid >> 6, lane = tid & 63;
    const int g = lane >> 4, li = lane & 15;
    const int wr = w >> 1, wc = w & 1;
    const float scale = (z == 0) ? 0.125f : 1.0f;

    if (z < 2) {
        bf16* C = (z == 0) ? Qh : Kh;
#pragma unroll
        for (int mf = 0; mf < 4; ++mf)
#pragma unroll
            for (int nf = 0; nf < 4; ++nf) {
                int m0 = bm0 + wr * 64 + mf * 16 + g * 4;
                int n = bn0 + wc * 64 + nf * 16 + li;
#pragma unroll
                for (int r = 0; r < 4; ++r)
                    C[(size_t)(m0 + r) * NN + n] = (bf16)(acc[mf][nf][r] * scale);
            }
    } else {
#pragma unroll
        for (int mf = 0; mf < 4; ++mf)
#pragma unroll
            for (int nf = 0; nf < 4; ++nf) {
                int m0 = bm0 + wr * 64 + mf * 16 + g * 4;
                int n = bn0 + wc * 64 + nf * 16 + li;
                int bq = m0 >> 11, tok = m0 & (N_ - 1);
                int hh = n >> 6, dv = n & 63;
                bf4 val;
#pragma unroll
                for (int r = 0; r < 4; ++r) val.v[r] = (bf16)acc[mf][nf][r];
                *(bf4*)(Vt + ((size_t)((bq * H_ + hh) * 64 + dv)) * N_ + tok) = val;
            }
    }
}

// output GEMM: out = Ob @ WoT^T + resid
__global__ __launch_bounds__(256) void k_out(const bf16* __restrict__ Ob,
                                             const bf16* __restrict__ WoT,
                                             float* __restrict__ outp,
                                             const float* __restrict__ resid) {
    __shared__ __align__(16) bf16 As[128 * 64];
    __shared__ __align__(16) bf16 Bs[128 * 64];
    int bid = blockIdx.x;
    int swz = (bid & 7) * 32 + (bid >> 3);
    int bm0 = (swz >> 3) * 128, bn0 = (swz & 7) * 128;

    f32x4 acc[4][4];
    mm_core(Ob, WoT, bm0, bn0, As, Bs, acc);

    const int tid = threadIdx.x, w = tid >> 6, lane = tid & 63;
    const int g = lane >> 4, li = lane & 15;
    const int wr = w >> 1, wc = w & 1;
#pragma unroll
    for (int mf = 0; mf < 4; ++mf)
#pragma unroll
        for (int nf = 0; nf < 4; ++nf) {
            int m0 = bm0 + wr * 64 + mf * 16 + g * 4;
            int n = bn0 + wc * 64 + nf * 16 + li;
#pragma unroll
            for (int r = 0; r < 4; ++r) {
                size_t ix = (size_t)(m0 + r) * NN + n;
                outp[ix] = acc[mf][nf][r] + resid[ix];
            }
        }
}

// ---------------------------------------------------------------- attention
// 1 wave per block, 16 q-rows per slice, paired slices (s, 127-s) -> flat work.
// K/V read straight from global (L2-resident per (b,h)); no __syncthreads.
// Block id mapping pins each (b,h) to one XCD: id%8 == (h*2+b)%8.
__global__ __launch_bounds__(64) void k_attn(const bf16* __restrict__ Qh,
                                             const bf16* __restrict__ Kh,
                                             const bf16* __restrict__ Vt,
                                             const uint32_t* __restrict__ bits,
                                             float* __restrict__ attnp,
                                             bf16* __restrict__ Ob) {
    __shared__ __align__(16) char Ps[16 * LDS_STRIDE];
    const int lane = threadIdx.x;
    const int g = lane >> 4, li = lane & 15;
    // decode block: xcd-pinned (b,h)
    const int id = blockIdx.x;          // 0..2047
    const int xcd = id & 7, slot = id >> 3;       // slot 0..255
    const int c = xcd + 8 * (slot & 3);           // combo 0..31
    const int p = slot >> 2;                      // pair 0..63
    const int h = c >> 1, b = c & 1;

    const size_t cbase = ((size_t)b * N_) * D_ + h * 64;
    const size_t vbase = ((size_t)(b * H_ + h) * 64) * N_;
    const f32x4 zz = {0.f, 0.f, 0.f, 0.f};

    for (int half = 0; half < 2; ++half) {
        const int sl = half ? (127 - p) : p;   // slice 0..127 (16 rows)
        const int qs0 = sl << 4;
        const int jt_max = sl >> 2;
        const size_t abase = (((size_t)b * H_ + h) * N_ + qs0) * (size_t)N_;

        const bf16* qptr = Qh + cbase + (size_t)(qs0 + li) * D_ + g * 8;
        const bf16x8 qf0 = *(const bf16x8*)qptr;
        const bf16x8 qf1 = *(const bf16x8*)(qptr + 32);
        const uint32_t* mrow = bits + (((size_t)b * N_ + qs0 + li) << 6);

        // ---------- pass A: row stats ----------
        float m = -1e30f, l = 0.f;
        for (int jt = 0; jt <= jt_max; ++jt) {
            const uint2 mw = *(const uint2*)(mrow + (jt << 1));
            const bf16* kptr = Kh + cbase + (size_t)(jt * 64 + li) * D_ + g * 8;
            f32x4 s[4];
#pragma unroll
            for (int mf = 0; mf < 4; ++mf) {
                bf16x8 k0 = *(const bf16x8*)(kptr + (size_t)(mf * 16) * D_);
                bf16x8 k1 = *(const bf16x8*)(kptr + (size_t)(mf * 16) * D_ + 32);
                s[mf] = __builtin_amdgcn_mfma_f32_16x16x32_bf16(k0, qf0, zz, 0, 0, 0);
                s[mf] = __builtin_amdgcn_mfma_f32_16x16x32_bf16(k1, qf1, s[mf], 0, 0, 0);
            }
            float tmax = m;
#pragma unroll
            for (int mf = 0; mf < 4; ++mf) {
                uint32_t wsel = (mf < 2) ? mw.x : mw.y;
#pragma unroll
                for (int r = 0; r < 4; ++r) {
                    int sh = (mf & 1) * 16 + g * 4 + r;
                    float xv = ((wsel >> sh) & 1) ? s[mf][r] : -1e9f;
                    s[mf][r] = xv;
                    tmax = fmaxf(tmax, xv);
                }
            }
            tmax = fmaxf(tmax, __shfl_xor(tmax, 16));
            tmax = fmaxf(tmax, __shfl_xor(tmax, 32));
            float ps = 0.f;
#pragma unroll
            for (int mf = 0; mf < 4; ++mf)
#pragma unroll
                for (int r = 0; r < 4; ++r) ps += __expf(s[mf][r] - tmax);
            ps += __shfl_xor(ps, 16);
            ps += __shfl_xor(ps, 32);
            l = l * __expf(m - tmax) + ps;
            m = tmax;
        }
        const float linv = 1.0f / l;

        // ---------- pass B: write P, O += P@V ----------
        f32x4 oacc[4];
#pragma unroll
        for (int nf = 0; nf < 4; ++nf) oacc[nf] = zz;

        for (int jt = 0; jt <= jt_max; ++jt) {
            const uint2 mw = *(const uint2*)(mrow + (jt << 1));
            const bf16* kptr = Kh + cbase + (size_t)(jt * 64 + li) * D_ + g * 8;
            f32x4 s[4];
#pragma unroll
            for (int mf = 0; mf < 4; ++mf) {
                bf16x8 k0 = *(const bf16x8*)(kptr + (size_t)(mf * 16) * D_);
                bf16x8 k1 = *(const bf16x8*)(kptr + (size_t)(mf * 16) * D_ + 32);
                s[mf] = __builtin_amdgcn_mfma_f32_16x16x32_bf16(k0, qf0, zz, 0, 0, 0);
                s[mf] = __builtin_amdgcn_mfma_f32_16x16x32_bf16(k1, qf1, s[mf], 0, 0, 0);
            }
#pragma unroll
            for (int mf = 0; mf < 4; ++mf) {
                uint32_t wsel = (mf < 2) ? mw.x : mw.y;
#pragma unroll
                for (int r = 0; r < 4; ++r) {
                    int sh = (mf & 1) * 16 + g * 4 + r;
                    float xv = ((wsel >> sh) & 1) ? s[mf][r] : -1e9f;
                    s[mf][r] = __expf(xv - m) * linv;
                }
                __builtin_nontemporal_store(s[mf],
                    (f32x4*)(attnp + abase + (size_t)li * N_ + (jt << 6) + mf * 16 + g * 4));
                bf4 pk;
#pragma unroll
                for (int r = 0; r < 4; ++r) pk.v[r] = (bf16)s[mf][r];
                *(bf4*)(Ps + li * LDS_STRIDE + (mf * 16 + g * 4) * 2) = pk;
            }
            // P fragments back (same wave -> lgkmcnt only)
            bf16x8 pf0 = *(const bf16x8*)(Ps + li * LDS_STRIDE + g * 16);
            bf16x8 pf1 = *(const bf16x8*)(Ps + li * LDS_STRIDE + 64 + g * 16);
            const bf16* vp = Vt + vbase + (size_t)li * N_ + (jt << 6) + g * 8;
#pragma unroll
            for (int nf = 0; nf < 4; ++nf) {
                bf16x8 v0 = *(const bf16x8*)(vp + (size_t)(nf * 16) * N_);
                bf16x8 v1 = *(const bf16x8*)(vp + (size_t)(nf * 16) * N_ + 32);
                oacc[nf] = __builtin_amdgcn_mfma_f32_16x16x32_bf16(pf0, v0, oacc[nf], 0, 0, 0);
                oacc[nf] = __builtin_amdgcn_mfma_f32_16x16x32_bf16(pf1, v1, oacc[nf], 0, 0, 0);
            }
        }
        // O store: row = qs0 + g*4 + r, col = h*64 + nf*16 + li
#pragma unroll
        for (int nf = 0; nf < 4; ++nf)
#pragma unroll
            for (int r = 0; r < 4; ++r) {
                int gi = qs0 + g * 4 + r;
                Ob[((size_t)(b * N_ + gi)) * D_ + h * 64 + nf * 16 + li] = (bf16)oacc[nf][r];
            }
        // zero-fill cols [ (jt_max+1)*64, N )
        const int z0 = (jt_max + 1) << 6;
        float* arow = attnp + abase + (size_t)li * N_;
        for (int c4 = (z0 >> 2) + g; c4 < N_ / 4; c4 += 4)
            __builtin_nontemporal_store(zz, (f32x4*)(arow + c4 * 4));
    }
}

// ---------------------------------------------------------------- layernorm
__global__ __launch_bounds__(256) void k_ln(float* __restrict__ out,
                                            const float* __restrict__ gamma,
                                            const float* __restrict__ beta) {
    const int row = blockIdx.x, t = threadIdx.x, lane = t & 63, w = t >> 6;
    float* p = out + (size_t)row * D_;
    f32x4 x = *(const f32x4*)(p + t * 4);
    float s = x[0] + x[1] + x[2] + x[3];
    float s2 = x[0] * x[0] + x[1] * x[1] + x[2] * x[2] + x[3] * x[3];
#pragma unroll
    for (int o = 1; o < 64; o <<= 1) {
        s += __shfl_xor(s, o);
        s2 += __shfl_xor(s2, o);
    }
    __shared__ float r1[4], r2[4];
    if (lane == 0) { r1[w] = s; r2[w] = s2; }
    __syncthreads();
    s = r1[0] + r1[1] + r1[2] + r1[3];
    s2 = r2[0] + r2[1] + r2[2] + r2[3];
    float mean = s * (1.f / D_);
    float var = s2 * (1.f / D_) - mean * mean;
    float rstd = rsqrtf(var + 1e-6f);
    f32x4 gv = *(const f32x4*)(gamma + t * 4);
    f32x4 bv = *(const f32x4*)(beta + t * 4);
    f32x4 y;
#pragma unroll
    for (int c = 0; c < 4; ++c) y[c] = (x[c] - mean) * rstd * gv[c] + bv[c];
    *(f32x4*)(p + t * 4) = y;
}

// ---------------------------------------------------------------- launch
extern "C" void kernel_launch(void* const* d_in, const int* in_sizes, int n_in,
                              void* d_out, int out_size, void* d_ws,
                              size_t ws_size, hipStream_t stream) {
    (void)in_sizes; (void)n_in; (void)out_size; (void)ws_size;
    const float* q = (const float*)d_in[0];
    const float* k = (const float*)d_in[1];
    const float* v = (const float*)d_in[2];
    const int* msk = (const int*)d_in[3];
    const float* Wq = (const float*)d_in[4];
    const float* Wk = (const float*)d_in[5];
    const float* Wv = (const float*)d_in[6];
    const float* Wo = (const float*)d_in[7];
    const float* gamma = (const float*)d_in[8];
    const float* beta = (const float*)d_in[9];

    float* outp = (float*)d_out;
    float* attnp = outp + (size_t)B_ * N_ * D_;

    const size_t U = (size_t)B_ * N_ * D_;
    const size_t W1 = (size_t)D_ * D_;
    bf16* ws = (bf16*)d_ws;
    bf16* qb = ws;   ws += U;
    bf16* kb = ws;   ws += U;
    bf16* vb = ws;   ws += U;
    bf16* WqT = ws;  ws += W1;
    bf16* WkT = ws;  ws += W1;
    bf16* WvT = ws;  ws += W1;
    bf16* WoT = ws;  ws += W1;
    bf16* Qh = ws;   ws += U;
    bf16* Kh = ws;   ws += U;
    bf16* Vt = ws;   ws += U;
    bf16* Ob = ws;   ws += U;
    uint32_t* bits = (uint32_t*)ws;  // 1 MB

    k_cvt3<<<dim3(U / 8 / 256, 3), 256, 0, stream>>>(q, k, v, qb, kb, vb);
    k_wtt4<<<dim3(32, 32, 4), dim3(32, 8), 0, stream>>>(Wq, Wk, Wv, Wo, WqT, WkT, WvT, WoT);
    k_bits<<<(size_t)B_ * N_ * N_ / 256, 256, 0, stream>>>(msk, bits);

    k_proj<<<dim3(256, 3), 256, 0, stream>>>(qb, kb, vb, WqT, WkT, WvT, Qh, Kh, Vt);

    k_attn<<<2048, 64, 0, stream>>>(Qh, Kh, Vt, bits, attnp, Ob);

    k_out<<<256, 256, 0, stream>>>(Ob, WoT, outp, q);

    k_ln<<<B_ * N_, 256, 0, stream>>>(outp, gamma, beta);
}

// Round 5
// 306.764 us; speedup vs baseline: 1.1122x; 1.1122x over previous
//
#include <hip/hip_runtime.h>
#include <hip/hip_bf16.h>
#include <stdint.h>

#define B_ 2
#define N_ 2048
#define D_ 1024
#define H_ 16
#define MM 4096
#define NN 1024
#define KK 1024

typedef __bf16 bf16;
typedef __bf16 bf16x8 __attribute__((ext_vector_type(8)));
typedef float f32x4 __attribute__((ext_vector_type(4)));

struct __align__(8) bf4 { bf16 v[4]; };

#define LDS_STRIDE 144
#define LOG2E 1.44269504088896340736f

#define GLDS(gp, lp)                                                     \
    __builtin_amdgcn_global_load_lds(                                    \
        (const __attribute__((address_space(1))) void*)(gp),             \
        (__attribute__((address_space(3))) void*)(lp), 16, 0, 0)

// ---------------------------------------------------------------- conversions
__global__ __launch_bounds__(256) void k_cvt3(const float* __restrict__ q,
                                              const float* __restrict__ k,
                                              const float* __restrict__ v,
                                              bf16* __restrict__ qb,
                                              bf16* __restrict__ kb,
                                              bf16* __restrict__ vb) {
    const int z = blockIdx.y;
    const float* s = z == 0 ? q : z == 1 ? k : v;
    bf16* d = z == 0 ? qb : z == 1 ? kb : vb;
    size_t i = ((size_t)blockIdx.x * 256 + threadIdx.x) * 8;
    f32x4 a = *(const f32x4*)(s + i);
    f32x4 b = *(const f32x4*)(s + i + 4);
    bf16x8 o;
#pragma unroll
    for (int j = 0; j < 4; ++j) { o[j] = (bf16)a[j]; o[4 + j] = (bf16)b[j]; }
    *(bf16x8*)(d + i) = o;
}

// Wt[n][k] = (bf16)W[k][n], z picks which weight (1024x1024)
__global__ void k_wtt4(const float* __restrict__ Wq, const float* __restrict__ Wk,
                       const float* __restrict__ Wv, const float* __restrict__ Wo,
                       bf16* __restrict__ WqT, bf16* __restrict__ WkT,
                       bf16* __restrict__ WvT, bf16* __restrict__ WoT) {
    const int z = blockIdx.z;
    const float* W = z == 0 ? Wq : z == 1 ? Wk : z == 2 ? Wv : Wo;
    bf16* Wt = z == 0 ? WqT : z == 1 ? WkT : z == 2 ? WvT : WoT;
    __shared__ float t[32][33];
    int bx = blockIdx.x * 32, by = blockIdx.y * 32;
    int tx = threadIdx.x, ty = threadIdx.y;
#pragma unroll
    for (int j = 0; j < 32; j += 8)
        t[ty + j][tx] = W[(size_t)(by + ty + j) * 1024 + bx + tx];
    __syncthreads();
#pragma unroll
    for (int j = 0; j < 32; j += 8)
        Wt[(size_t)(bx + ty + j) * 1024 + by + tx] = (bf16)t[tx][ty + j];
}

// ---------------------------------------------------------------- mask bits
__global__ __launch_bounds__(256) void k_bits(const int* __restrict__ mask,
                                              uint32_t* __restrict__ bits) {
    size_t flat = (size_t)blockIdx.x * 256 + threadIdx.x;
    int col = (int)(flat & (N_ - 1));
    int row = (int)((flat >> 11) & (N_ - 1));
    bool ok = (mask[flat] != 0) && (col <= row);
    unsigned long long bal = __ballot(ok);
    if ((threadIdx.x & 63) == 0)
        *(unsigned long long*)(bits + (flat >> 5)) = bal;
}

// ---------------------------------------------------------------- GEMM core
// C = A @ Bt^T, 128x128 tile, BK=64, 4 waves, global_load_lds w=16 (m97).
__device__ __forceinline__ void mm_core(const bf16* __restrict__ A,
                                        const bf16* __restrict__ Bt,
                                        int bm0, int bn0,
                                        bf16* As, bf16* Bs,
                                        f32x4 (&acc)[4][4]) {
    const int tid = threadIdx.x, w = tid >> 6, lane = tid & 63;
    const int g = lane >> 4, li = lane & 15;
    const int wr = w >> 1, wc = w & 1;

    f32x4 zz = {0.f, 0.f, 0.f, 0.f};
#pragma unroll
    for (int mf = 0; mf < 4; ++mf)
#pragma unroll
        for (int nf = 0; nf < 4; ++nf) acc[mf][nf] = zz;

    auto stage = [&](int k0) {
#pragma unroll
        for (int c = 0; c < 4; ++c) {
            int ch = c * 256 + tid;
            int r = ch >> 3, cl = ch & 7;
            GLDS(A + (size_t)(bm0 + r) * KK + k0 + cl * 8,
                 As + ((size_t)c * 256 + w * 64) * 8);
        }
#pragma unroll
        for (int c = 0; c < 4; ++c) {
            int ch = c * 256 + tid;
            int r = ch >> 3, cl = ch & 7;
            GLDS(Bt + (size_t)(bn0 + r) * KK + k0 + cl * 8,
                 Bs + ((size_t)c * 256 + w * 64) * 8);
        }
    };

    stage(0);
    for (int s = 0; s < KK / 64; ++s) {
        __syncthreads();
#pragma unroll
        for (int kk = 0; kk < 2; ++kk) {
            bf16x8 af[4], bfr[4];
#pragma unroll
            for (int i = 0; i < 4; ++i) {
                af[i] = *(const bf16x8*)(As + (wr * 64 + i * 16 + li) * 64 + kk * 32 + g * 8);
                bfr[i] = *(const bf16x8*)(Bs + (wc * 64 + i * 16 + li) * 64 + kk * 32 + g * 8);
            }
#pragma unroll
            for (int mf = 0; mf < 4; ++mf)
#pragma unroll
                for (int nf = 0; nf < 4; ++nf)
                    acc[mf][nf] = __builtin_amdgcn_mfma_f32_16x16x32_bf16(
                        af[mf], bfr[nf], acc[mf][nf], 0, 0, 0);
        }
        __syncthreads();
        if (s + 1 < KK / 64) stage((s + 1) * 64);
    }
}

// fused Q/K/V projections (Q scaled by 0.125*log2e for exp2-softmax)
__global__ __launch_bounds__(256) void k_proj(const bf16* __restrict__ qb,
                                              const bf16* __restrict__ kb,
                                              const bf16* __restrict__ vb,
                                              const bf16* __restrict__ WqT,
                                              const bf16* __restrict__ WkT,
                                              const bf16* __restrict__ WvT,
                                              bf16* __restrict__ Qh,
                                              bf16* __restrict__ Kh,
                                              bf16* __restrict__ Vt) {
    __shared__ __align__(16) bf16 As[128 * 64];
    __shared__ __align__(16) bf16 Bs[128 * 64];
    const int z = blockIdx.y;
    const bf16* A = z == 0 ? qb : z == 1 ? kb : vb;
    const bf16* Bt = z == 0 ? WqT : z == 1 ? WkT : WvT;
    int bid = blockIdx.x;
    int swz = (bid & 7) * 32 + (bid >> 3);
    int bm0 = (swz >> 3) * 128, bn0 = (swz & 7) * 128;

    f32x4 acc[4][4];
    mm_core(A, Bt, bm0, bn0, As, Bs, acc);

    const int tid = threadIdx.x, w = tid >> 6, lane = tid & 63;
    const int g = lane >> 4, li = lane & 15;
    const int wr = w >> 1, wc = w & 1;
    const float scale = (z == 0) ? 0.125f * LOG2E : 1.0f;

    if (z < 2) {
        bf16* C = (z == 0) ? Qh : Kh;
#pragma unroll
        for (int mf = 0; mf < 4; ++mf)
#pragma unroll
            for (int nf = 0; nf < 4; ++nf) {
                int m0 = bm0 + wr * 64 + mf * 16 + g * 4;
                int n = bn0 + wc * 64 + nf * 16 + li;
#pragma unroll
                for (int r = 0; r < 4; ++r)
                    C[(size_t)(m0 + r) * NN + n] = (bf16)(acc[mf][nf][r] * scale);
            }
    } else {
#pragma unroll
        for (int mf = 0; mf < 4; ++mf)
#pragma unroll
            for (int nf = 0; nf < 4; ++nf) {
                int m0 = bm0 + wr * 64 + mf * 16 + g * 4;
                int n = bn0 + wc * 64 + nf * 16 + li;
                int bq = m0 >> 11, tok = m0 & (N_ - 1);
                int hh = n >> 6, dv = n & 63;
                bf4 val;
#pragma unroll
                for (int r = 0; r < 4; ++r) val.v[r] = (bf16)acc[mf][nf][r];
                *(bf4*)(Vt + ((size_t)((bq * H_ + hh) * 64 + dv)) * N_ + tok) = val;
            }
    }
}

// output GEMM: out = Ob @ WoT^T + resid
__global__ __launch_bounds__(256) void k_out(const bf16* __restrict__ Ob,
                                             const bf16* __restrict__ WoT,
                                             float* __restrict__ outp,
                                             const float* __restrict__ resid) {
    __shared__ __align__(16) bf16 As[128 * 64];
    __shared__ __align__(16) bf16 Bs[128 * 64];
    int bid = blockIdx.x;
    int swz = (bid & 7) * 32 + (bid >> 3);
    int bm0 = (swz >> 3) * 128, bn0 = (swz & 7) * 128;

    f32x4 acc[4][4];
    mm_core(Ob, WoT, bm0, bn0, As, Bs, acc);

    const int tid = threadIdx.x, w = tid >> 6, lane = tid & 63;
    const int g = lane >> 4, li = lane & 15;
    const int wr = w >> 1, wc = w & 1;
#pragma unroll
    for (int mf = 0; mf < 4; ++mf)
#pragma unroll
        for (int nf = 0; nf < 4; ++nf) {
            int m0 = bm0 + wr * 64 + mf * 16 + g * 4;
            int n = bn0 + wc * 64 + nf * 16 + li;
#pragma unroll
            for (int r = 0; r < 4; ++r) {
                size_t ix = (size_t)(m0 + r) * NN + n;
                outp[ix] = acc[mf][nf][r] + resid[ix];
            }
        }
}

// ---------------------------------------------------------------- attention
// Round-2 structure (proven): block = (pair p, h, b), qt = p and 31-p.
// Swapped QK^T; single-buffered K/V; 2 barriers/tile; reg prefetch.
// Scores arrive pre-scaled by 0.125*log2e -> softmax in exp2 domain.
__global__ __launch_bounds__(256) void k_attn(const bf16* __restrict__ Qh,
                                              const bf16* __restrict__ Kh,
                                              const bf16* __restrict__ Vt,
                                              const uint32_t* __restrict__ bits,
                                              float* __restrict__ attnp,
                                              bf16* __restrict__ Ob) {
    __shared__ __align__(16) char Qs[64 * LDS_STRIDE];
    __shared__ __align__(16) char Ks[64 * LDS_STRIDE];
    __shared__ __align__(16) char Vs[64 * LDS_STRIDE];
    __shared__ __align__(16) char Ps[64 * LDS_STRIDE];
    const int tid = threadIdx.x, lane = tid & 63, w = tid >> 6;
    const int g = lane >> 4, li = lane & 15;
    const int p = blockIdx.x, h = blockIdx.y, b = blockIdx.z;
    const int srow = tid >> 3, sc = tid & 7;
    const int myrow = w * 16 + li;

    const size_t kbase = ((size_t)b * N_) * D_ + h * 64;
    const size_t vbase = ((size_t)(b * H_ + h) * 64) * N_;
    f32x4 zz = {0.f, 0.f, 0.f, 0.f};

    for (int half = 0; half < 2; ++half) {
        const int qt = half ? (31 - p) : p;
        const int i0 = qt << 6;
        const size_t abase = (((size_t)b * H_ + h) * N_ + i0) * (size_t)N_;

        __syncthreads();  // previous half's LDS reads done
        {  // stage Q
            const char* qsrc = (const char*)Qh +
                (kbase + (size_t)(i0 + srow) * D_ + sc * 8) * 2;
            bf16x8 t0 = *(const bf16x8*)qsrc;
            bf16x8 t1 = *(const bf16x8*)(qsrc + (size_t)32 * D_ * 2);
            *(bf16x8*)(Qs + srow * LDS_STRIDE + sc * 16) = t0;
            *(bf16x8*)(Qs + (srow + 32) * LDS_STRIDE + sc * 16) = t1;
        }
        const uint32_t* mrow = bits + (((size_t)b * N_ + i0 + myrow) << 6);

        // ================= pass A: row stats =================
        float m = -1e30f, l = 0.f;
        bf16x8 ka, kb2, va, vb2;
        {
            const char* ks = (const char*)Kh + (kbase + (size_t)srow * D_ + sc * 8) * 2;
            ka = *(const bf16x8*)ks;
            kb2 = *(const bf16x8*)(ks + (size_t)32 * D_ * 2);
        }
        for (int jt = 0; jt <= qt; ++jt) {
            __syncthreads();
            *(bf16x8*)(Ks + srow * LDS_STRIDE + sc * 16) = ka;
            *(bf16x8*)(Ks + (srow + 32) * LDS_STRIDE + sc * 16) = kb2;
            {
                int jn = (jt < qt) ? jt + 1 : qt;
                const char* ks = (const char*)Kh +
                    (kbase + (size_t)(jn * 64 + srow) * D_ + sc * 8) * 2;
                ka = *(const bf16x8*)ks;
                kb2 = *(const bf16x8*)(ks + (size_t)32 * D_ * 2);
            }
            uint2 mw = *(const uint2*)(mrow + (jt << 1));
            __syncthreads();

            f32x4 s[4];
#pragma unroll
            for (int mf = 0; mf < 4; ++mf) s[mf] = zz;
#pragma unroll
            for (int kk = 0; kk < 2; ++kk) {
                const int kb = kk * 64 + (g << 4);
                bf16x8 qf = *(const bf16x8*)(Qs + myrow * LDS_STRIDE + kb);
#pragma unroll
                for (int mf = 0; mf < 4; ++mf) {
                    bf16x8 kf = *(const bf16x8*)(Ks + (mf * 16 + li) * LDS_STRIDE + kb);
                    s[mf] = __builtin_amdgcn_mfma_f32_16x16x32_bf16(kf, qf, s[mf], 0, 0, 0);
                }
            }
            float tmax = m;
#pragma unroll
            for (int mf = 0; mf < 4; ++mf) {
                uint32_t wsel = (mf < 2) ? mw.x : mw.y;
#pragma unroll
                for (int r = 0; r < 4; ++r) {
                    int sh = (mf & 1) * 16 + g * 4 + r;
                    float xv = ((wsel >> sh) & 1) ? s[mf][r] : -1e9f;
                    s[mf][r] = xv;
                    tmax = fmaxf(tmax, xv);
                }
            }
            tmax = fmaxf(tmax, __shfl_xor(tmax, 16));
            tmax = fmaxf(tmax, __shfl_xor(tmax, 32));
            float ps = 0.f;
#pragma unroll
            for (int mf = 0; mf < 4; ++mf)
#pragma unroll
                for (int r = 0; r < 4; ++r) ps += exp2f(s[mf][r] - tmax);
            ps += __shfl_xor(ps, 16);
            ps += __shfl_xor(ps, 32);
            l = l * exp2f(m - tmax) + ps;
            m = tmax;
        }
        const float ml = m + __log2f(l);  // P = exp2(x - ml)

        // ================= pass B: P + O =================
        f32x4 oacc[4];
#pragma unroll
        for (int nf = 0; nf < 4; ++nf) oacc[nf] = zz;

        {
            const char* ks = (const char*)Kh + (kbase + (size_t)srow * D_ + sc * 8) * 2;
            ka = *(const bf16x8*)ks;
            kb2 = *(const bf16x8*)(ks + (size_t)32 * D_ * 2);
            const char* vs = (const char*)Vt + (vbase + (size_t)srow * N_ + sc * 8) * 2;
            va = *(const bf16x8*)vs;
            vb2 = *(const bf16x8*)(vs + (size_t)32 * N_ * 2);
        }
        for (int jt = 0; jt <= qt; ++jt) {
            __syncthreads();
            *(bf16x8*)(Ks + srow * LDS_STRIDE + sc * 16) = ka;
            *(bf16x8*)(Ks + (srow + 32) * LDS_STRIDE + sc * 16) = kb2;
            *(bf16x8*)(Vs + srow * LDS_STRIDE + sc * 16) = va;
            *(bf16x8*)(Vs + (srow + 32) * LDS_STRIDE + sc * 16) = vb2;
            {
                int jn = (jt < qt) ? jt + 1 : qt;
                const char* ks = (const char*)Kh +
                    (kbase + (size_t)(jn * 64 + srow) * D_ + sc * 8) * 2;
                ka = *(const bf16x8*)ks;
                kb2 = *(const bf16x8*)(ks + (size_t)32 * D_ * 2);
                const char* vs = (const char*)Vt +
                    (vbase + (size_t)srow * N_ + jn * 64 + sc * 8) * 2;
                va = *(const bf16x8*)vs;
                vb2 = *(const bf16x8*)(vs + (size_t)32 * N_ * 2);
            }
            uint2 mw = *(const uint2*)(mrow + (jt << 1));
            __syncthreads();

            f32x4 s[4];
#pragma unroll
            for (int mf = 0; mf < 4; ++mf) s[mf] = zz;
#pragma unroll
            for (int kk = 0; kk < 2; ++kk) {
                const int kb = kk * 64 + (g << 4);
                bf16x8 qf = *(const bf16x8*)(Qs + myrow * LDS_STRIDE + kb);
#pragma unroll
                for (int mf = 0; mf < 4; ++mf) {
                    bf16x8 kf = *(const bf16x8*)(Ks + (mf * 16 + li) * LDS_STRIDE + kb);
                    s[mf] = __builtin_amdgcn_mfma_f32_16x16x32_bf16(kf, qf, s[mf], 0, 0, 0);
                }
            }

#pragma unroll
            for (int mf = 0; mf < 4; ++mf) {
                uint32_t wsel = (mf < 2) ? mw.x : mw.y;
#pragma unroll
                for (int r = 0; r < 4; ++r) {
                    int sh = (mf & 1) * 16 + g * 4 + r;
                    float xv = ((wsel >> sh) & 1) ? s[mf][r] : -1e9f;
                    s[mf][r] = exp2f(xv - ml);
                }
                __builtin_nontemporal_store(s[mf],
                    (f32x4*)(attnp + abase + (size_t)myrow * N_ + (jt << 6) + mf * 16 + g * 4));
                bf4 pk;
#pragma unroll
                for (int r = 0; r < 4; ++r) pk.v[r] = (bf16)s[mf][r];
                *(bf4*)(Ps + myrow * LDS_STRIDE + (mf * 16 + g * 4) * 2) = pk;
            }
            // PV (Ps rows written/read by same wave)
#pragma unroll
            for (int kk = 0; kk < 2; ++kk) {
                const int kb = kk * 64 + (g << 4);
                bf16x8 pf = *(const bf16x8*)(Ps + myrow * LDS_STRIDE + kb);
#pragma unroll
                for (int nf = 0; nf < 4; ++nf) {
                    bf16x8 vf = *(const bf16x8*)(Vs + (nf * 16 + li) * LDS_STRIDE + kb);
                    oacc[nf] = __builtin_amdgcn_mfma_f32_16x16x32_bf16(pf, vf, oacc[nf], 0, 0, 0);
                }
            }
        }
        // O store
#pragma unroll
        for (int nf = 0; nf < 4; ++nf)
#pragma unroll
            for (int r = 0; r < 4; ++r) {
                int gi = i0 + w * 16 + g * 4 + r;
                Ob[((size_t)(b * N_ + gi)) * D_ + h * 64 + nf * 16 + li] = (bf16)oacc[nf][r];
            }
        // zero-fill strictly-upper tiles
        int zc0 = i0 + 64;
        if (zc0 < N_) {
            int r = tid >> 2, tc = tid & 3;
            f32x4 z = zz;
            for (int c = zc0 + tc * 4; c < N_; c += 16)
                __builtin_nontemporal_store(z, (f32x4*)(attnp + abase + (size_t)r * N_ + c));
        }
    }
}

// ---------------------------------------------------------------- layernorm
__global__ __launch_bounds__(256) void k_ln(float* __restrict__ out,
                                            const float* __restrict__ gamma,
                                            const float* __restrict__ beta) {
    const int row = blockIdx.x, t = threadIdx.x, lane = t & 63, w = t >> 6;
    float* p = out + (size_t)row * D_;
    f32x4 x = *(const f32x4*)(p + t * 4);
    float s = x[0] + x[1] + x[2] + x[3];
    float s2 = x[0] * x[0] + x[1] * x[1] + x[2] * x[2] + x[3] * x[3];
#pragma unroll
    for (int o = 1; o < 64; o <<= 1) {
        s += __shfl_xor(s, o);
        s2 += __shfl_xor(s2, o);
    }
    __shared__ float r1[4], r2[4];
    if (lane == 0) { r1[w] = s; r2[w] = s2; }
    __syncthreads();
    s = r1[0] + r1[1] + r1[2] + r1[3];
    s2 = r2[0] + r2[1] + r2[2] + r2[3];
    float mean = s * (1.f / D_);
    float var = s2 * (1.f / D_) - mean * mean;
    float rstd = rsqrtf(var + 1e-6f);
    f32x4 gv = *(const f32x4*)(gamma + t * 4);
    f32x4 bv = *(const f32x4*)(beta + t * 4);
    f32x4 y;
#pragma unroll
    for (int c = 0; c < 4; ++c) y[c] = (x[c] - mean) * rstd * gv[c] + bv[c];
    *(f32x4*)(p + t * 4) = y;
}

// ---------------------------------------------------------------- launch
extern "C" void kernel_launch(void* const* d_in, const int* in_sizes, int n_in,
                              void* d_out, int out_size, void* d_ws,
                              size_t ws_size, hipStream_t stream) {
    (void)in_sizes; (void)n_in; (void)out_size; (void)ws_size;
    const float* q = (const float*)d_in[0];
    const float* k = (const float*)d_in[1];
    const float* v = (const float*)d_in[2];
    const int* msk = (const int*)d_in[3];
    const float* Wq = (const float*)d_in[4];
    const float* Wk = (const float*)d_in[5];
    const float* Wv = (const float*)d_in[6];
    const float* Wo = (const float*)d_in[7];
    const float* gamma = (const float*)d_in[8];
    const float* beta = (const float*)d_in[9];

    float* outp = (float*)d_out;
    float* attnp = outp + (size_t)B_ * N_ * D_;

    const size_t U = (size_t)B_ * N_ * D_;
    const size_t W1 = (size_t)D_ * D_;
    bf16* ws = (bf16*)d_ws;
    bf16* qb = ws;   ws += U;
    bf16* kb = ws;   ws += U;
    bf16* vb = ws;   ws += U;
    bf16* WqT = ws;  ws += W1;
    bf16* WkT = ws;  ws += W1;
    bf16* WvT = ws;  ws += W1;
    bf16* WoT = ws;  ws += W1;
    bf16* Qh = ws;   ws += U;
    bf16* Kh = ws;   ws += U;
    bf16* Vt = ws;   ws += U;
    bf16* Ob = ws;   ws += U;
    uint32_t* bits = (uint32_t*)ws;  // 1 MB

    k_cvt3<<<dim3(U / 8 / 256, 3), 256, 0, stream>>>(q, k, v, qb, kb, vb);
    k_wtt4<<<dim3(32, 32, 4), dim3(32, 8), 0, stream>>>(Wq, Wk, Wv, Wo, WqT, WkT, WvT, WoT);
    k_bits<<<(size_t)B_ * N_ * N_ / 256, 256, 0, stream>>>(msk, bits);

    k_proj<<<dim3(256, 3), 256, 0, stream>>>(qb, kb, vb, WqT, WkT, WvT, Qh, Kh, Vt);

    k_attn<<<dim3(16, H_, B_), 256, 0, stream>>>(Qh, Kh, Vt, bits, attnp, Ob);

    k_out<<<256, 256, 0, stream>>>(Ob, WoT, outp, q);

    k_ln<<<B_ * N_, 256, 0, stream>>>(outp, gamma, beta);
}